// Round 5
// baseline (51.715 us; speedup 1.0000x reference)
//
#include <hip/hip_runtime.h>

typedef __attribute__((ext_vector_type(8)))  __bf16 bf16x8;
typedef __attribute__((ext_vector_type(16))) float  f32x16;

#define DEV __device__ __forceinline__

namespace {

constexpr int BB = 32, CC = 3, TT = 2048, KK = 128, OUTK = 384;
constexpr int TP = 2176;   // padded x-copy row length (elements)

// ---- workspace byte offsets ----
constexpr size_t OFF_B16 = 0;                       // 3*4*1*64 uint4 = 12288 B
constexpr size_t OFF_B32 = 12288;                   // 24576 B
constexpr size_t OFF_B64 = 36864;                   // 49152 B
constexpr size_t OFF_S2  = 86016;                   // [3][CC][KK] f32 = 4608 B
constexpr size_t OFF_X2  = 90624;                   // [3][BB][CC][TT] f32 = 2359296 B
constexpr size_t OFF_XC  = 2449920;                 // [BB][CC][8][TP] bf16 = 3342336 B

DEV unsigned short rne(float f) {
  unsigned u = __float_as_uint(f);
  u += 0x7FFFu + ((u >> 16) & 1u);
  return (unsigned short)(u >> 16);
}
DEV float rnef(float f) {
  unsigned u = __float_as_uint(f);
  u += 0x7FFFu + ((u >> 16) & 1u);
  return __uint_as_float(u & 0xFFFF0000u);
}
DEV uint4 pack8(const unsigned short* h) {
  uint4 d;
  d.x = (unsigned)h[0] | ((unsigned)h[1] << 16);
  d.y = (unsigned)h[2] | ((unsigned)h[3] << 16);
  d.z = (unsigned)h[4] | ((unsigned)h[5] << 16);
  d.w = (unsigned)h[6] | ((unsigned)h[7] << 16);
  return d;
}
DEV float f4get(const float4 v, int j) {
  switch (j) { case 0: return v.x; case 1: return v.y; case 2: return v.z; default: return v.w; }
}

// ---------------- precompute (identical to round 4, verified) ----------------
constexpr int N_OUT = BB * OUTK;
constexpr int N_BF  = 5376;
constexpr int N_S2  = 1152;
constexpr int N_XC  = BB * CC * 8 * (TP/8);
constexpr int N_X2  = BB * CC * TT;
constexpr int N_TOT = N_OUT + N_BF + N_S2 + N_XC + N_X2;

__global__ __launch_bounds__(256) void precompute(
    const float* __restrict__ x, const float* __restrict__ sh16,
    const float* __restrict__ sh32, const float* __restrict__ sh64,
    unsigned char* __restrict__ ws, unsigned* __restrict__ outu)
{
  int i = blockIdx.x * 256 + threadIdx.x;
  if (i >= N_TOT) return;
  if (i < N_OUT) { outu[i] = 0x7f800000u; return; }
  i -= N_OUT;

  if (i < N_BF) {
    int S, it; const float* sh; size_t boff;
    if (i < 768)       { S = 16; it = i;        sh = sh16; boff = OFF_B16; }
    else if (i < 2304) { S = 32; it = i - 768;  sh = sh32; boff = OFF_B32; }
    else               { S = 64; it = i - 2304; sh = sh64; boff = OFF_B64; }
    const int CHS = S / 8, KST = S / 16;
    int c = it / (KK * CHS); int r = it - c * KK * CHS;
    int n = r / CHS;         int k0 = (r - n * CHS) * 8;
    const float* src = sh + ((size_t)(c * KK + n)) * S + k0;
    unsigned short h[8];
    #pragma unroll
    for (int j = 0; j < 8; ++j) h[j] = rne(src[j]);
    ((uint4*)(ws + boff))[((c * 4 + (n >> 5)) * KST + (k0 >> 4)) * 64 + ((k0 >> 3) & 1) * 32 + (n & 31)] = pack8(h);
    return;
  }
  i -= N_BF;

  if (i < N_S2) {
    int Sidx = i / 384; int r = i - Sidx * 384; int c = r >> 7; int k = r & 127;
    int S = 16 << Sidx;
    const float* sh = (Sidx == 0) ? sh16 : ((Sidx == 1) ? sh32 : sh64);
    const float* sp = sh + ((size_t)(c * KK + k)) * S;
    float acc = 0.f;
    #pragma unroll 4
    for (int s = 0; s < S; ++s) { float v = rnef(sp[s]); acc = fmaf(v, v, acc); }
    ((float*)(ws + OFF_S2))[(Sidx * CC + c) * KK + k] = acc;
    return;
  }
  i -= N_S2;

  if (i < N_XC) {
    const int per = TP / 8;
    int c8 = i / per; int q8 = i - c8 * per;
    int p  = c8 & 7;  int bc = c8 >> 3;
    const float* xb = x + (size_t)bc * TT;
    int m0 = q8 * 8;
    unsigned short h[8];
    #pragma unroll
    for (int j = 0; j < 8; ++j) {
      int mi = m0 + j + p;
      float v = (mi < TT) ? xb[mi] : 0.f;
      h[j] = rne(v);
    }
    ((uint4*)(ws + OFF_XC + (size_t)c8 * TP * 2))[q8] = pack8(h);
    return;
  }
  i -= N_XC;

  {
    int w = i & (TT - 1); int bc = i >> 11;
    const float* xb = x + (size_t)bc * TT;
    float acc = 0.f, a16, a32, a64;
    #pragma unroll 4
    for (int s = 0; s < 16; ++s) { int mi = w + s; float v = (mi < TT) ? rnef(xb[mi]) : 0.f; acc = fmaf(v, v, acc); }
    a16 = acc;
    #pragma unroll 4
    for (int s = 16; s < 32; ++s) { int mi = w + s; float v = (mi < TT) ? rnef(xb[mi]) : 0.f; acc = fmaf(v, v, acc); }
    a32 = acc;
    #pragma unroll 4
    for (int s = 32; s < 64; ++s) { int mi = w + s; float v = (mi < TT) ? rnef(xb[mi]) : 0.f; acc = fmaf(v, v, acc); }
    a64 = acc;
    float* x2 = (float*)(ws + OFF_X2);
    x2[(size_t)(0 * BB * CC + bc) * TT + w] = a16;
    x2[(size_t)(1 * BB * CC + bc) * TT + w] = a32;
    x2[(size_t)(2 * BB * CC + bc) * TT + w] = a64;
  }
}

// ---------------- main: LDS-free, barrier-free, 64w x 32k per wave ----------------
template<int S, int KST, int OUTOFF, size_t BOFF, int SIDX>
DEV void run(const unsigned char* __restrict__ ws, unsigned* __restrict__ outu,
             int b, int wt)
{
  const int tid = (int)threadIdx.x;
  const int lane = tid & 63, kq = tid >> 6;
  const int l31 = lane & 31, lhi = lane >> 5, p = l31 & 7;
  const int w0 = wt * 64;

  const float* x2g = (const float*)(ws + OFF_X2) + (size_t)(SIDX * BB * CC + b * CC) * TT + w0;
  const float* s2g = (const float*)(ws + OFF_S2) + SIDX * CC * KK + kq * 32 + l31;
  const uint4* Bg = (const uint4*)(ws + BOFF);
  const unsigned short* XCb = (const unsigned short*)(ws + OFF_XC);

  f32x16 dlo{}, dhi{};
  #pragma unroll
  for (int c = 0; c < CC; ++c) {
    f32x16 alo{}, ahi{};
    const unsigned short* xcg = XCb + (size_t)((b * CC + c) * 8 + p) * TP;
    const int e0 = w0 + l31 - p + 8 * lhi;   // multiple of 8 -> 16B aligned
    #pragma unroll
    for (int kk = 0; kk < KST; ++kk) {
      bf16x8 A0 = __builtin_bit_cast(bf16x8, *(const uint4*)(xcg + e0 + 16 * kk));
      bf16x8 A1 = __builtin_bit_cast(bf16x8, *(const uint4*)(xcg + e0 + 16 * kk + 32));
      bf16x8 Bv = __builtin_bit_cast(bf16x8, Bg[((c * 4 + kq) * KST + kk) * 64 + lane]);
      alo = __builtin_amdgcn_mfma_f32_32x32x16_bf16(A0, Bv, alo, 0, 0, 0);
      ahi = __builtin_amdgcn_mfma_f32_32x32x16_bf16(A1, Bv, ahi, 0, 0, 0);
    }
    const float s2c = s2g[c * KK];                      // coalesced 128B segment
    const float* x2c = x2g + (size_t)c * TT;
    #pragma unroll
    for (int g = 0; g < 4; ++g) {
      // broadcast float4 loads: all lanes in an lhi-half read the same address
      const float4 xl = *(const float4*)(x2c + 4 * lhi + 8 * g);
      const float4 xh = *(const float4*)(x2c + 4 * lhi + 8 * g + 32);
      #pragma unroll
      for (int j = 0; j < 4; ++j) {
        const int r2 = g * 4 + j;                       // ro = j + 8g + 4lhi
        dlo[r2] += __builtin_amdgcn_sqrtf(fmaxf(fmaf(-2.f, alo[r2], f4get(xl, j) + s2c), 1e-12f));
        dhi[r2] += __builtin_amdgcn_sqrtf(fmaxf(fmaf(-2.f, ahi[r2], f4get(xh, j) + s2c), 1e-12f));
      }
    }
  }

  constexpr int W = TT - S + 1;
  float m = __builtin_inff();
  if (wt != 31) {                                       // all 64 rows valid (W-64 >= 1921)
    #pragma unroll
    for (int r2 = 0; r2 < 16; ++r2) m = fminf(m, fminf(dlo[r2], dhi[r2]));
  } else {
    #pragma unroll
    for (int r2 = 0; r2 < 16; ++r2) {
      const int ro = (r2 & 3) + 8 * (r2 >> 2) + 4 * lhi;
      if (w0 + ro < W)      m = fminf(m, dlo[r2]);
      if (w0 + 32 + ro < W) m = fminf(m, dhi[r2]);
    }
  }
  m = fminf(m, __shfl_xor(m, 32));
  if (lane < 32)
    atomicMin(outu + (b * OUTK + OUTOFF + kq * 32 + l31), __float_as_uint(m));
}

__global__ __launch_bounds__(256, 4) void shapelets_main(
    const unsigned char* __restrict__ ws, unsigned* __restrict__ outu)
{
  const int j = (int)blockIdx.x;
  if (j < 1024) {                       // contiguous S-ranges: I-cache locality
    run<16, 1,   0, OFF_B16, 0>(ws, outu, j >> 5, j & 31);
  } else if (j < 2048) {
    const int r = j - 1024;
    run<32, 2, 128, OFF_B32, 1>(ws, outu, r >> 5, r & 31);
  } else {
    const int r = j - 2048;
    run<64, 4, 256, OFF_B64, 2>(ws, outu, r >> 5, r & 31);
  }
}

} // namespace

extern "C" void kernel_launch(void* const* d_in, const int* in_sizes, int n_in,
                              void* d_out, int out_size, void* d_ws, size_t ws_size,
                              hipStream_t stream) {
  const float* x    = (const float*)d_in[0];
  const float* sh16 = (const float*)d_in[1];
  const float* sh32 = (const float*)d_in[2];
  const float* sh64 = (const float*)d_in[3];
  unsigned* outu = (unsigned*)d_out;
  unsigned char* ws = (unsigned char*)d_ws;

  precompute<<<(N_TOT + 255) / 256, 256, 0, stream>>>(x, sh16, sh32, sh64, ws, outu);
  shapelets_main<<<3072, 256, 0, stream>>>(ws, outu);
}

// Round 7
// 47.640 us; speedup vs baseline: 1.0855x; 1.0855x over previous
//
#include <hip/hip_runtime.h>

typedef __attribute__((ext_vector_type(8)))  __bf16 bf16x8;
typedef __attribute__((ext_vector_type(16))) float  f32x16;

#define DEV __device__ __forceinline__

namespace {

constexpr int BB = 32, CC = 3, TT = 2048, KK = 128, OUTK = 384;
constexpr int TP = 2176;   // padded x-copy row length (elements)

// ---- workspace byte offsets ----
constexpr size_t OFF_B16 = 0;                       // B-frags S16
constexpr size_t OFF_B32 = 12288;
constexpr size_t OFF_B64 = 36864;
constexpr size_t OFF_S2  = 86016;                   // [3][CC][KK] f32
constexpr size_t OFF_X2  = 90624;                   // [3][BB][CC][TT] f32
constexpr size_t OFF_XC  = 2449920;                 // [BB][CC][8][TP] bf16

DEV unsigned short rne(float f) {
  unsigned u = __float_as_uint(f);
  u += 0x7FFFu + ((u >> 16) & 1u);
  return (unsigned short)(u >> 16);
}
DEV float rnef(float f) {
  unsigned u = __float_as_uint(f);
  u += 0x7FFFu + ((u >> 16) & 1u);
  return __uint_as_float(u & 0xFFFF0000u);
}
DEV uint4 pack8(const unsigned short* h) {
  uint4 d;
  d.x = (unsigned)h[0] | ((unsigned)h[1] << 16);
  d.y = (unsigned)h[2] | ((unsigned)h[3] << 16);
  d.z = (unsigned)h[4] | ((unsigned)h[5] << 16);
  d.w = (unsigned)h[6] | ((unsigned)h[7] << 16);
  return d;
}
DEV float f4get(const float4 v, int j) {
  switch (j) { case 0: return v.x; case 1: return v.y; case 2: return v.z; default: return v.w; }
}

// ---------------- precompute (identical to round 4/5, verified) ----------------
constexpr int N_OUT = BB * OUTK;
constexpr int N_BF  = 5376;
constexpr int N_S2  = 1152;
constexpr int N_XC  = BB * CC * 8 * (TP/8);
constexpr int N_X2  = BB * CC * TT;
constexpr int N_TOT = N_OUT + N_BF + N_S2 + N_XC + N_X2;

__global__ __launch_bounds__(256) void precompute(
    const float* __restrict__ x, const float* __restrict__ sh16,
    const float* __restrict__ sh32, const float* __restrict__ sh64,
    unsigned char* __restrict__ ws, unsigned* __restrict__ outu)
{
  int i = blockIdx.x * 256 + threadIdx.x;
  if (i >= N_TOT) return;
  if (i < N_OUT) { outu[i] = 0x7f800000u; return; }
  i -= N_OUT;

  if (i < N_BF) {
    int S, it; const float* sh; size_t boff;
    if (i < 768)       { S = 16; it = i;        sh = sh16; boff = OFF_B16; }
    else if (i < 2304) { S = 32; it = i - 768;  sh = sh32; boff = OFF_B32; }
    else               { S = 64; it = i - 2304; sh = sh64; boff = OFF_B64; }
    const int CHS = S / 8, KST = S / 16;
    int c = it / (KK * CHS); int r = it - c * KK * CHS;
    int n = r / CHS;         int k0 = (r - n * CHS) * 8;
    const float* src = sh + ((size_t)(c * KK + n)) * S + k0;
    unsigned short h[8];
    #pragma unroll
    for (int j = 0; j < 8; ++j) h[j] = rne(src[j]);
    ((uint4*)(ws + boff))[((c * 4 + (n >> 5)) * KST + (k0 >> 4)) * 64 + ((k0 >> 3) & 1) * 32 + (n & 31)] = pack8(h);
    return;
  }
  i -= N_BF;

  if (i < N_S2) {
    int Sidx = i / 384; int r = i - Sidx * 384; int c = r >> 7; int k = r & 127;
    int S = 16 << Sidx;
    const float* sh = (Sidx == 0) ? sh16 : ((Sidx == 1) ? sh32 : sh64);
    const float* sp = sh + ((size_t)(c * KK + k)) * S;
    float acc = 0.f;
    #pragma unroll 4
    for (int s = 0; s < S; ++s) { float v = rnef(sp[s]); acc = fmaf(v, v, acc); }
    ((float*)(ws + OFF_S2))[(Sidx * CC + c) * KK + k] = acc;
    return;
  }
  i -= N_S2;

  if (i < N_XC) {
    const int per = TP / 8;
    int c8 = i / per; int q8 = i - c8 * per;
    int p  = c8 & 7;  int bc = c8 >> 3;
    const float* xb = x + (size_t)bc * TT;
    int m0 = q8 * 8;
    unsigned short h[8];
    #pragma unroll
    for (int j = 0; j < 8; ++j) {
      int mi = m0 + j + p;
      float v = (mi < TT) ? xb[mi] : 0.f;
      h[j] = rne(v);
    }
    ((uint4*)(ws + OFF_XC + (size_t)c8 * TP * 2))[q8] = pack8(h);
    return;
  }
  i -= N_XC;

  {
    int w = i & (TT - 1); int bc = i >> 11;
    const float* xb = x + (size_t)bc * TT;
    float acc = 0.f, a16, a32, a64;
    #pragma unroll 4
    for (int s = 0; s < 16; ++s) { int mi = w + s; float v = (mi < TT) ? rnef(xb[mi]) : 0.f; acc = fmaf(v, v, acc); }
    a16 = acc;
    #pragma unroll 4
    for (int s = 16; s < 32; ++s) { int mi = w + s; float v = (mi < TT) ? rnef(xb[mi]) : 0.f; acc = fmaf(v, v, acc); }
    a32 = acc;
    #pragma unroll 4
    for (int s = 32; s < 64; ++s) { int mi = w + s; float v = (mi < TT) ? rnef(xb[mi]) : 0.f; acc = fmaf(v, v, acc); }
    a64 = acc;
    float* x2 = (float*)(ws + OFF_X2);
    x2[(size_t)(0 * BB * CC + bc) * TT + w] = a16;
    x2[(size_t)(1 * BB * CC + bc) * TT + w] = a32;
    x2[(size_t)(2 * BB * CC + bc) * TT + w] = a64;
  }
}

// ---------------- main: 32w x 32k per wave, channel-pipelined loads ----------------
template<int KST> struct Frag { uint4 A[KST]; uint4 B[KST]; };

template<int KST>
DEV void issueAB(const unsigned short* __restrict__ xA, const uint4* __restrict__ bB, Frag<KST>& F) {
  #pragma unroll
  for (int kk = 0; kk < KST; ++kk) {
    F.A[kk] = *(const uint4*)(xA + 16 * kk);
    F.B[kk] = bB[kk * 64];
  }
}
template<int KST>
DEV f32x16 domfma(const Frag<KST>& F) {
  f32x16 a{};
  #pragma unroll
  for (int kk = 0; kk < KST; ++kk)
    a = __builtin_amdgcn_mfma_f32_32x32x16_bf16(
        __builtin_bit_cast(bf16x8, F.A[kk]), __builtin_bit_cast(bf16x8, F.B[kk]), a, 0, 0, 0);
  return a;
}
DEV void epi(const f32x16 a, const float* __restrict__ x2c, float s2c, int lhi, f32x16& dsum) {
  #pragma unroll
  for (int g = 0; g < 4; ++g) {
    const float4 xq = *(const float4*)(x2c + 4 * lhi + 8 * g);   // LDS, broadcast, aligned
    #pragma unroll
    for (int j = 0; j < 4; ++j) {
      const int r2 = g * 4 + j;
      dsum[r2] += __builtin_amdgcn_sqrtf(fmaxf(fmaf(-2.f, a[r2], f4get(xq, j) + s2c), 1e-12f));
    }
  }
}

template<int S, int KST, int OUTOFF, size_t BOFF, int SIDX>
DEV void run(const unsigned char* __restrict__ ws, unsigned* __restrict__ outu,
             int r, float* __restrict__ x2l, float* __restrict__ s2l)
{
  const int b = r >> 6, t = r & 63, wblk = t >> 1, kblk = t & 1;
  const int tid = (int)threadIdx.x;
  const int lane = tid & 63;
  const int l31 = lane & 31, lhi = lane >> 5, p = l31 & 7;
  const int wsub = (tid >> 6) & 1, ksub = tid >> 7;
  const int w0 = wblk * 64 + wsub * 32;
  const int kq = kblk * 2 + ksub;                 // 32-wide k quarter

  // ---- block stage: x2 (3x64) + s2 (3x64) -> LDS, one barrier ----
  // (round-6 bug fix: threads 0..191 load BOTH tables; 192..383 don't exist)
  const float* x2g = (const float*)(ws + OFF_X2) + (size_t)(SIDX * BB * CC + b * CC) * TT;
  const float* s2g = (const float*)(ws + OFF_S2) + SIDX * CC * KK;
  if (tid < 192) {
    int c = tid >> 6, w = tid & 63;
    x2l[tid] = x2g[(size_t)c * TT + wblk * 64 + w];
    s2l[tid] = s2g[c * KK + kblk * 64 + w];
  }
  __syncthreads();

  // ---- per-wave pointers (c=0; channel strides: A += 8*TP, B += 4*KST*64) ----
  const unsigned short* xA = (const unsigned short*)(ws + OFF_XC)
      + ((size_t)(b * CC * 8) + p) * TP + (w0 + 8 * (l31 >> 3) + 8 * lhi);
  const uint4* bB = (const uint4*)(ws + BOFF) + (size_t)(kq * KST) * 64 + lane;

  Frag<KST> F0, F1, F2;
  issueAB<KST>(xA, bB, F0);
  issueAB<KST>(xA + 8 * TP, bB + 4 * KST * 64, F1);

  f32x16 dsum{};
  const float* x2w = x2l + wsub * 32;
  const float s20 = s2l[0 * 64 + ksub * 32 + l31];
  const float s21 = s2l[1 * 64 + ksub * 32 + l31];
  const float s22 = s2l[2 * 64 + ksub * 32 + l31];

  f32x16 a0 = domfma<KST>(F0);
  issueAB<KST>(xA + 16 * TP, bB + 8 * KST * 64, F2);
  epi(a0, x2w + 0 * 64, s20, lhi, dsum);
  f32x16 a1 = domfma<KST>(F1);
  epi(a1, x2w + 1 * 64, s21, lhi, dsum);
  f32x16 a2 = domfma<KST>(F2);
  epi(a2, x2w + 2 * 64, s22, lhi, dsum);

  // ---- min + write ----
  constexpr int W = TT - S + 1;
  float m = __builtin_inff();
  if (w0 + 31 < W) {
    #pragma unroll
    for (int r2 = 0; r2 < 16; ++r2) m = fminf(m, dsum[r2]);
  } else {
    #pragma unroll
    for (int r2 = 0; r2 < 16; ++r2) {
      const int ro = (r2 & 3) + 8 * (r2 >> 2) + 4 * lhi;
      if (w0 + ro < W) m = fminf(m, dsum[r2]);
    }
  }
  m = fminf(m, __shfl_xor(m, 32));
  if (lane < 32)
    atomicMin(outu + (b * OUTK + OUTOFF + kq * 32 + l31), __float_as_uint(m));
}

__global__ __launch_bounds__(256, 2) void shapelets_main(
    const unsigned char* __restrict__ ws, unsigned* __restrict__ outu)
{
  __shared__ __attribute__((aligned(16))) float x2l[192];
  __shared__ __attribute__((aligned(16))) float s2l[192];
  const int j = (int)blockIdx.x;
  if (j < 2048)      run<16, 1,   0, OFF_B16, 0>(ws, outu, j,        x2l, s2l);
  else if (j < 4096) run<32, 2, 128, OFF_B32, 1>(ws, outu, j - 2048, x2l, s2l);
  else               run<64, 4, 256, OFF_B64, 2>(ws, outu, j - 4096, x2l, s2l);
}

} // namespace

extern "C" void kernel_launch(void* const* d_in, const int* in_sizes, int n_in,
                              void* d_out, int out_size, void* d_ws, size_t ws_size,
                              hipStream_t stream) {
  const float* x    = (const float*)d_in[0];
  const float* sh16 = (const float*)d_in[1];
  const float* sh32 = (const float*)d_in[2];
  const float* sh64 = (const float*)d_in[3];
  unsigned* outu = (unsigned*)d_out;
  unsigned char* ws = (unsigned char*)d_ws;

  precompute<<<(N_TOT + 255) / 256, 256, 0, stream>>>(x, sh16, sh32, sh64, ws, outu);
  shapelets_main<<<6144, 256, 0, stream>>>(ws, outu);
}

// Round 8
// 39.634 us; speedup vs baseline: 1.3048x; 1.2020x over previous
//
#include <hip/hip_runtime.h>

typedef __attribute__((ext_vector_type(8)))  __bf16 bf16x8;
typedef __attribute__((ext_vector_type(16))) float  f32x16;

#define DEV __device__ __forceinline__

namespace {

constexpr int BB = 32, CC = 3, TT = 2048, KK = 128, OUTK = 384;
constexpr int TP = 2176;   // padded x-copy row length (elements)

// ---- workspace byte offsets ----
constexpr size_t OFF_B16 = 0;                       // B-frags S16
constexpr size_t OFF_B32 = 12288;
constexpr size_t OFF_B64 = 36864;
constexpr size_t OFF_S2  = 86016;                   // [3][CC][KK] f32
constexpr size_t OFF_X2  = 90624;                   // [3][BB][CC][TT] f32
constexpr size_t OFF_XC  = 2449920;                 // [BB][CC][8][TP] bf16

DEV unsigned short rne(float f) {
  unsigned u = __float_as_uint(f);
  u += 0x7FFFu + ((u >> 16) & 1u);
  return (unsigned short)(u >> 16);
}
DEV float rnef(float f) {
  unsigned u = __float_as_uint(f);
  u += 0x7FFFu + ((u >> 16) & 1u);
  return __uint_as_float(u & 0xFFFF0000u);
}
DEV uint4 pack8(const unsigned short* h) {
  uint4 d;
  d.x = (unsigned)h[0] | ((unsigned)h[1] << 16);
  d.y = (unsigned)h[2] | ((unsigned)h[3] << 16);
  d.z = (unsigned)h[4] | ((unsigned)h[5] << 16);
  d.w = (unsigned)h[6] | ((unsigned)h[7] << 16);
  return d;
}
DEV float f4get(const float4 v, int j) {
  switch (j) { case 0: return v.x; case 1: return v.y; case 2: return v.z; default: return v.w; }
}

// ---------------- precompute (identical to rounds 4-7, verified) ----------------
constexpr int N_OUT = BB * OUTK;
constexpr int N_BF  = 5376;
constexpr int N_S2  = 1152;
constexpr int N_XC  = BB * CC * 8 * (TP/8);
constexpr int N_X2  = BB * CC * TT;
constexpr int N_TOT = N_OUT + N_BF + N_S2 + N_XC + N_X2;

__global__ __launch_bounds__(256) void precompute(
    const float* __restrict__ x, const float* __restrict__ sh16,
    const float* __restrict__ sh32, const float* __restrict__ sh64,
    unsigned char* __restrict__ ws, unsigned* __restrict__ outu)
{
  int i = blockIdx.x * 256 + threadIdx.x;
  if (i >= N_TOT) return;
  if (i < N_OUT) { outu[i] = 0x7f800000u; return; }
  i -= N_OUT;

  if (i < N_BF) {
    int S, it; const float* sh; size_t boff;
    if (i < 768)       { S = 16; it = i;        sh = sh16; boff = OFF_B16; }
    else if (i < 2304) { S = 32; it = i - 768;  sh = sh32; boff = OFF_B32; }
    else               { S = 64; it = i - 2304; sh = sh64; boff = OFF_B64; }
    const int CHS = S / 8, KST = S / 16;
    int c = it / (KK * CHS); int r = it - c * KK * CHS;
    int n = r / CHS;         int k0 = (r - n * CHS) * 8;
    const float* src = sh + ((size_t)(c * KK + n)) * S + k0;
    unsigned short h[8];
    #pragma unroll
    for (int j = 0; j < 8; ++j) h[j] = rne(src[j]);
    ((uint4*)(ws + boff))[((c * 4 + (n >> 5)) * KST + (k0 >> 4)) * 64 + ((k0 >> 3) & 1) * 32 + (n & 31)] = pack8(h);
    return;
  }
  i -= N_BF;

  if (i < N_S2) {
    int Sidx = i / 384; int r = i - Sidx * 384; int c = r >> 7; int k = r & 127;
    int S = 16 << Sidx;
    const float* sh = (Sidx == 0) ? sh16 : ((Sidx == 1) ? sh32 : sh64);
    const float* sp = sh + ((size_t)(c * KK + k)) * S;
    float acc = 0.f;
    #pragma unroll 4
    for (int s = 0; s < S; ++s) { float v = rnef(sp[s]); acc = fmaf(v, v, acc); }
    ((float*)(ws + OFF_S2))[(Sidx * CC + c) * KK + k] = acc;
    return;
  }
  i -= N_S2;

  if (i < N_XC) {
    const int per = TP / 8;
    int c8 = i / per; int q8 = i - c8 * per;
    int p  = c8 & 7;  int bc = c8 >> 3;
    const float* xb = x + (size_t)bc * TT;
    int m0 = q8 * 8;
    unsigned short h[8];
    #pragma unroll
    for (int j = 0; j < 8; ++j) {
      int mi = m0 + j + p;
      float v = (mi < TT) ? xb[mi] : 0.f;
      h[j] = rne(v);
    }
    ((uint4*)(ws + OFF_XC + (size_t)c8 * TP * 2))[q8] = pack8(h);
    return;
  }
  i -= N_XC;

  {
    int w = i & (TT - 1); int bc = i >> 11;
    const float* xb = x + (size_t)bc * TT;
    float acc = 0.f, a16, a32, a64;
    #pragma unroll 4
    for (int s = 0; s < 16; ++s) { int mi = w + s; float v = (mi < TT) ? rnef(xb[mi]) : 0.f; acc = fmaf(v, v, acc); }
    a16 = acc;
    #pragma unroll 4
    for (int s = 16; s < 32; ++s) { int mi = w + s; float v = (mi < TT) ? rnef(xb[mi]) : 0.f; acc = fmaf(v, v, acc); }
    a32 = acc;
    #pragma unroll 4
    for (int s = 32; s < 64; ++s) { int mi = w + s; float v = (mi < TT) ? rnef(xb[mi]) : 0.f; acc = fmaf(v, v, acc); }
    a64 = acc;
    float* x2 = (float*)(ws + OFF_X2);
    x2[(size_t)(0 * BB * CC + bc) * TT + w] = a16;
    x2[(size_t)(1 * BB * CC + bc) * TT + w] = a32;
    x2[(size_t)(2 * BB * CC + bc) * TT + w] = a64;
  }
}

// ------------- main: fat waves — 32w rows, k-loop over full K=128 -------------
DEV void epi(const f32x16 a, const float* __restrict__ x2c, float s2c, int lhi, f32x16& dsum) {
  #pragma unroll
  for (int g = 0; g < 4; ++g) {
    const float4 xq = *(const float4*)(x2c + 4 * lhi + 8 * g);   // LDS broadcast, aligned
    #pragma unroll
    for (int j = 0; j < 4; ++j) {
      const int r2 = g * 4 + j;
      dsum[r2] += __builtin_amdgcn_sqrtf(fmaxf(fmaf(-2.f, a[r2], f4get(xq, j) + s2c), 1e-12f));
    }
  }
}

template<int S, int KST, int OUTOFF, size_t BOFF, int SIDX>
DEV void run(const unsigned char* __restrict__ ws, unsigned* __restrict__ outu,
             int r, float* __restrict__ x2l, float* __restrict__ s2l)
{
  const int b = r >> 4, wg = r & 15;          // 16 w-groups of 128
  const int tid = (int)threadIdx.x;
  const int lane = tid & 63, wsub = tid >> 6;
  const int l31 = lane & 31, lhi = lane >> 5, p = l31 & 7;
  const int w0 = wg * 128 + wsub * 32;

  // ---- one-shot block stage: x2[3][128] (this w-group) + s2[3][128] (full K) ----
  const float* x2g = (const float*)(ws + OFF_X2) + (size_t)(SIDX * BB * CC + b * CC) * TT + wg * 128;
  const float* s2g = (const float*)(ws + OFF_S2) + SIDX * CC * KK;
  #pragma unroll
  for (int i0 = 0; i0 < 2; ++i0) {
    int i = i0 * 256 + tid;
    if (i < 384) {
      int c = i >> 7, q = i & 127;
      x2l[i] = x2g[(size_t)c * TT + q];
      s2l[i] = s2g[c * KK + q];
    }
  }
  __syncthreads();

  // ---- hoist A-fragments (verified layout): reused across all 4 kq ----
  const unsigned short* XCb = (const unsigned short*)(ws + OFF_XC);
  uint4 A[CC][KST];
  #pragma unroll
  for (int c = 0; c < CC; ++c) {
    const unsigned short* xA = XCb + ((size_t)((b * CC + c) * 8) + p) * TP
                             + (w0 + 8 * (l31 >> 3) + 8 * lhi);
    #pragma unroll
    for (int kk = 0; kk < KST; ++kk) A[c][kk] = *(const uint4*)(xA + 16 * kk);
  }

  const uint4* Bg = (const uint4*)(ws + BOFF) + lane;
  constexpr int W = TT - S + 1;

  #pragma unroll
  for (int kq = 0; kq < 4; ++kq) {
    f32x16 dsum{};
    #pragma unroll
    for (int c = 0; c < CC; ++c) {
      uint4 Bf[KST];
      #pragma unroll
      for (int kk = 0; kk < KST; ++kk)
        Bf[kk] = Bg[(size_t)(((c * 4 + kq) * KST + kk)) * 64];
      f32x16 acc{};
      #pragma unroll
      for (int kk = 0; kk < KST; ++kk)
        acc = __builtin_amdgcn_mfma_f32_32x32x16_bf16(
            __builtin_bit_cast(bf16x8, A[c][kk]), __builtin_bit_cast(bf16x8, Bf[kk]), acc, 0, 0, 0);
      const float s2c = s2l[c * 128 + kq * 32 + l31];
      epi(acc, x2l + c * 128 + wsub * 32, s2c, lhi, dsum);
    }
    // ---- min over rows + cross-half + atomic ----
    float m = __builtin_inff();
    if (w0 + 31 < W) {                       // wave-uniform fast path
      #pragma unroll
      for (int r2 = 0; r2 < 16; ++r2) m = fminf(m, dsum[r2]);
    } else {
      #pragma unroll
      for (int r2 = 0; r2 < 16; ++r2) {
        const int ro = (r2 & 3) + 8 * (r2 >> 2) + 4 * lhi;
        if (w0 + ro < W) m = fminf(m, dsum[r2]);
      }
    }
    m = fminf(m, __shfl_xor(m, 32));
    if (lane < 32)
      atomicMin(outu + (b * OUTK + OUTOFF + kq * 32 + l31), __float_as_uint(m));
  }
}

__global__ __launch_bounds__(256, 3) void shapelets_main(
    const unsigned char* __restrict__ ws, unsigned* __restrict__ outu)
{
  __shared__ __attribute__((aligned(16))) float x2l[384];
  __shared__ __attribute__((aligned(16))) float s2l[384];
  const int j = (int)blockIdx.x;
  if (j < 512)       run<16, 1,   0, OFF_B16, 0>(ws, outu, j,        x2l, s2l);
  else if (j < 1024) run<32, 2, 128, OFF_B32, 1>(ws, outu, j - 512,  x2l, s2l);
  else               run<64, 4, 256, OFF_B64, 2>(ws, outu, j - 1024, x2l, s2l);
}

} // namespace

extern "C" void kernel_launch(void* const* d_in, const int* in_sizes, int n_in,
                              void* d_out, int out_size, void* d_ws, size_t ws_size,
                              hipStream_t stream) {
  const float* x    = (const float*)d_in[0];
  const float* sh16 = (const float*)d_in[1];
  const float* sh32 = (const float*)d_in[2];
  const float* sh64 = (const float*)d_in[3];
  unsigned* outu = (unsigned*)d_out;
  unsigned char* ws = (unsigned char*)d_ws;

  precompute<<<(N_TOT + 255) / 256, 256, 0, stream>>>(x, sh16, sh32, sh64, ws, outu);
  shapelets_main<<<1536, 256, 0, stream>>>(ws, outu);
}